// Round 4
// baseline (257.324 us; speedup 1.0000x reference)
//
#include <hip/hip_runtime.h>
#include <hip/hip_bf16.h>

// NCA update, round 4: R3 design with the compile fix + A-frag load placement.
// Separable perception + nt-split MFMA + XOR-swizzled LDS.
// Numerics identical to R2: Y and W1/W2 split hi/lo bf16 (hh+hl+lh passes),
// H single bf16. fp32 epilogue.

#define CCH 16
#define HID 128
#define HH 256
#define WW 256
#define BB 32

typedef __attribute__((ext_vector_type(8))) short bf16x8;
typedef __attribute__((ext_vector_type(4))) float f32x4;
typedef __attribute__((ext_vector_type(4))) unsigned int u32x4;
typedef __attribute__((ext_vector_type(2))) unsigned int u32x2;

__device__ inline unsigned short f2bf(float f) {  // RNE
  unsigned int u = __float_as_uint(f);
  u += 0x7FFFu + ((u >> 16) & 1u);
  return (unsigned short)(u >> 16);
}
__device__ inline float bf2f(unsigned short s) {
  return __uint_as_float(((unsigned int)s) << 16);
}
__device__ inline unsigned int cvtpk2(float a, float b) {  // v_cvt_pk_bf16_f32
  union { __hip_bfloat162 h; unsigned int u; } cv;
  cv.h = __float22bfloat162_rn(make_float2(a, b));
  return cv.u;
}

// ---------------------------------------------------------------- prep
// w1p[(((pl*2+ks)*8 + mt)*64 + lane)*8 + j]; row = mt*16+(l&15),
// k = ks*32+(l>>4)*8+j; k>=48 zeroed (pairs with the dup-B-read trick).
__global__ __launch_bounds__(256) void pack_w1_kernel(
    const float* __restrict__ w1, unsigned short* __restrict__ w1p) {
  const int tid = blockIdx.x * 256 + threadIdx.x;
  if (tid >= 2048) return;
  const int l = tid & 63, m = (tid >> 6) & 7, ks = (tid >> 9) & 1,
            pl = (tid >> 10) & 1;
  const int row = m * 16 + (l & 15);
  const int kb = ks * 32 + (l >> 4) * 8;
  const size_t off = ((((size_t)pl * 2 + ks) * 8 + m) * 64 + l) * 8;
#pragma unroll
  for (int j = 0; j < 8; ++j) {
    const int k = kb + j;
    const float v = (k < 48) ? w1[row * 48 + k] : 0.0f;
    const unsigned short hi = f2bf(v);
    w1p[off + j] = (pl == 0) ? hi : f2bf(v - bf2f(hi));
  }
}

// w2p[((pl*4+ks)*64 + lane)*8 + j]; row = l&15, k = ks*32+(l>>4)*8+j.
__global__ __launch_bounds__(256) void pack_w2_kernel(
    const float* __restrict__ w2, unsigned short* __restrict__ w2p) {
  const int tid = blockIdx.x * 256 + threadIdx.x;
  if (tid >= 512) return;
  const int l = tid & 63, ks = (tid >> 6) & 3, pl = (tid >> 8) & 1;
  const int row = l & 15;
  const int kb = ks * 32 + (l >> 4) * 8;
  const size_t off = (((size_t)pl * 4 + ks) * 64 + l) * 8;
#pragma unroll
  for (int j = 0; j < 8; ++j) {
    const float v = w2[row * 128 + kb + j];
    const unsigned short hi = f2bf(v);
    w2p[off + j] = (pl == 0) ? hi : f2bf(v - bf2f(hi));
  }
}

// ---------------------------------------------------------------- main
// Block = 128 px (half row), 256 thr = 4 waves. LDS 64 KB:
//   region0 32 KB: phase1 = a[130][20]f32 | b | id | colmax ; phase3+ = H[128][128]bf16
//   region1 16 KB: Yh[128][64]bf16 (XOR-swizzled)
//   region2 16 KB: Yl
__global__ __launch_bounds__(256, 2) void nca_mfma_kernel(
    const float* __restrict__ x, const float* __restrict__ b1,
    const float* __restrict__ b2, const unsigned short* __restrict__ w1p,
    const unsigned short* __restrict__ w2p, const int* __restrict__ fire,
    float* __restrict__ out, float* __restrict__ alpha_ws,
    unsigned char* __restrict__ pre_ws) {
  __shared__ __align__(16) unsigned char smem[65536];
  float* fre = (float*)smem;
  unsigned short* Hs = (unsigned short*)smem;
  unsigned char* Yh = smem + 32768;
  unsigned char* Yl = smem + 49152;

  const int L = blockIdx.x;
  const int orig = ((L & 7) << 11) + (L >> 3);  // XCD-contiguous (16384=8*2048)
  const int b = orig >> 9;
  const int h = (orig >> 1) & 255;
  const int wt = orig & 1;
  const int tid = threadIdx.x;
  const int wv = tid >> 6, lane = tid & 63, g = lane >> 4, ln = lane & 15;
  const int hm = (h + 255) & 255, hp = (h + 1) & 255;

  // ---- phase 1a: staging + vertical filter.
  // 520 units = 130 cols x 4 ch-groups; a=.125(t+b)+.25m, bb=.125(b-t), id=m.
  {
    const float* xb0 = x + (size_t)b * CCH * HH * WW;
    for (int u = tid; u < 520; u += 256) {
      const int cg = (u >= 390) ? 3 : (u >= 260) ? 2 : (u >= 130) ? 1 : 0;
      const int col = u - cg * 130;
      const int pxg = (wt * 128 + col + 255) & 255;
      f32x4 av, bv, iv;
      float cmax = 0.0f;
#pragma unroll
      for (int j = 0; j < 4; ++j) {
        const float* xc = xb0 + (size_t)(cg * 4 + j) * (HH * WW) + pxg;
        const float t = xc[hm * WW];
        const float m = xc[h * WW];
        const float bo = xc[hp * WW];
        av[j] = 0.125f * (t + bo) + 0.25f * m;
        bv[j] = 0.125f * (bo - t);
        iv[j] = m;
        if (cg == 0 && j == 3) cmax = fmaxf(fmaxf(t, m), bo);
      }
      const int dw = col * 20 + cg * 4;  // stride 20 dw: aligned
      *(f32x4*)(fre + dw) = av;
      *(f32x4*)(fre + 2600 + dw) = bv;
      *(f32x4*)(fre + 5200 + dw) = iv;
      if (cg == 0) fre[7800 + col] = cmax;
    }
  }

  // A1 preload here: issues before the barrier, latency hides under phase 1b.
  bf16x8 A1[8][4];  // [mt][hi-k0, hi-k1, lo-k0, lo-k1]
#pragma unroll
  for (int mt = 0; mt < 8; ++mt)
#pragma unroll
    for (int f = 0; f < 4; ++f)
      A1[mt][f] =
          *(const bf16x8*)(w1p + (((size_t)f * 8 + mt) * 64 + lane) * 8);

  __syncthreads();

  // ---- phase 1b: horizontal filter -> split-bf16 Y (swizzled).
  {
    const int px = tid & 127;
    const int c0h = (tid >> 7) * 8;  // 0 or 8
    const int base = (px + 1) * 20 + c0h;
    float aL[8], aR[8], bL[8], bC[8], bR[8], iC[8];
    *(f32x4*)(aL) = *(const f32x4*)(fre + base - 20);
    *(f32x4*)(aL + 4) = *(const f32x4*)(fre + base - 16);
    *(f32x4*)(aR) = *(const f32x4*)(fre + base + 20);
    *(f32x4*)(aR + 4) = *(const f32x4*)(fre + base + 24);
    *(f32x4*)(bL) = *(const f32x4*)(fre + 2600 + base - 20);
    *(f32x4*)(bL + 4) = *(const f32x4*)(fre + 2600 + base - 16);
    *(f32x4*)(bC) = *(const f32x4*)(fre + 2600 + base);
    *(f32x4*)(bC + 4) = *(const f32x4*)(fre + 2600 + base + 4);
    *(f32x4*)(bR) = *(const f32x4*)(fre + 2600 + base + 20);
    *(f32x4*)(bR + 4) = *(const f32x4*)(fre + 2600 + base + 24);
    *(f32x4*)(iC) = *(const f32x4*)(fre + 5200 + base);
    *(f32x4*)(iC + 4) = *(const f32x4*)(fre + 5200 + base + 4);

    float yv[24];
#pragma unroll
    for (int j = 0; j < 8; ++j) {
      yv[j * 3 + 0] = iC[j];
      yv[j * 3 + 1] = aR[j] - aL[j];
      yv[j * 3 + 2] = bL[j] + 2.0f * bC[j] + bR[j];
    }
    unsigned int hw[12], lw[12];
#pragma unroll
    for (int i = 0; i < 12; ++i) {
      const unsigned int hp2 = cvtpk2(yv[2 * i], yv[2 * i + 1]);
      hw[i] = hp2;
      const float r0 = yv[2 * i] - __uint_as_float(hp2 << 16);
      const float r1 = yv[2 * i + 1] - __uint_as_float(hp2 & 0xFFFF0000u);
      lw[i] = cvtpk2(r0, r1);
    }
    const int ybyte = px * 128 + c0h * 6;  // k-offset *2B: 0 or 48
    const int sw = (px & 7) << 4;
#pragma unroll
    for (int i = 0; i < 3; ++i) {
      u32x4 vh = {hw[4 * i], hw[4 * i + 1], hw[4 * i + 2], hw[4 * i + 3]};
      u32x4 vl = {lw[4 * i], lw[4 * i + 1], lw[4 * i + 2], lw[4 * i + 3]};
      *(u32x4*)(Yh + ((ybyte + i * 16) ^ sw)) = vh;
      *(u32x4*)(Yl + ((ybyte + i * 16) ^ sw)) = vl;
    }
    if (c0h == 0) {  // pre-life from column-max of alpha
      const float m0 = fre[7800 + px], m1 = fre[7801 + px], m2 = fre[7802 + px];
      const size_t pix = ((size_t)b * HH + h) * WW + wt * 128 + px;
      pre_ws[pix] = (fmaxf(fmaxf(m0, m1), m2) > 0.1f) ? 1 : 0;
    }
  }
  __syncthreads();

  // ---- phase 2: L1 GEMM, nt-split (wave owns px-tiles 2wv, 2wv+1).
  f32x4 acc[8][2];
#pragma unroll
  for (int mt = 0; mt < 8; ++mt)
#pragma unroll
    for (int ni = 0; ni < 2; ++ni) acc[mt][ni] = (f32x4){0.f, 0.f, 0.f, 0.f};

#pragma unroll
  for (int ni = 0; ni < 2; ++ni) {
    const int pxb = (wv * 2 + ni) * 16 + ln;
    const int sw = (pxb & 7) << 4;
    const int base = pxb * 128;
    const int off1 = (g < 2) ? (64 + g * 16) : ((g - 2) * 16);  // dup-read pad
    const bf16x8 Bh0 = *(const bf16x8*)(Yh + ((base + g * 16) ^ sw));
    const bf16x8 Bh1 = *(const bf16x8*)(Yh + ((base + off1) ^ sw));
    const bf16x8 Bl0 = *(const bf16x8*)(Yl + ((base + g * 16) ^ sw));
    const bf16x8 Bl1 = *(const bf16x8*)(Yl + ((base + off1) ^ sw));
#pragma unroll
    for (int mt = 0; mt < 8; ++mt) {
      f32x4 a = acc[mt][ni];
      a = __builtin_amdgcn_mfma_f32_16x16x32_bf16(A1[mt][0], Bh0, a, 0, 0, 0);
      a = __builtin_amdgcn_mfma_f32_16x16x32_bf16(A1[mt][1], Bh1, a, 0, 0, 0);
      a = __builtin_amdgcn_mfma_f32_16x16x32_bf16(A1[mt][2], Bh0, a, 0, 0, 0);
      a = __builtin_amdgcn_mfma_f32_16x16x32_bf16(A1[mt][3], Bh1, a, 0, 0, 0);
      a = __builtin_amdgcn_mfma_f32_16x16x32_bf16(A1[mt][0], Bl0, a, 0, 0, 0);
      a = __builtin_amdgcn_mfma_f32_16x16x32_bf16(A1[mt][1], Bl1, a, 0, 0, 0);
      acc[mt][ni] = a;
    }
  }
  // No barrier: phases 3/4 touch only this wave's px rows of region0, and
  // region0's separable arrays were last read before the second barrier.

  // ---- phase 3: bias+relu -> H bf16 (swizzled), wave-local.
#pragma unroll
  for (int ni = 0; ni < 2; ++ni) {
    const int pxb = (wv * 2 + ni) * 16 + ln;
    const int sw = (pxb & 7) << 4;
#pragma unroll
    for (int mt = 0; mt < 8; ++mt) {
      const f32x4 bv = *(const f32x4*)(b1 + mt * 16 + g * 4);
      const f32x4 a = acc[mt][ni];
      u32x2 hwv;
      hwv[0] = cvtpk2(fmaxf(a[0] + bv[0], 0.f), fmaxf(a[1] + bv[1], 0.f));
      hwv[1] = cvtpk2(fmaxf(a[2] + bv[2], 0.f), fmaxf(a[3] + bv[3], 0.f));
      *(u32x2*)((unsigned char*)Hs +
                ((pxb * 256 + (mt * 16 + g * 4) * 2) ^ sw)) = hwv;
    }
  }

  // ---- phase 4 + epilogue: L2 GEMM (K=128) + x+dx*fire, wave-local.
  bf16x8 A2[8];  // [pl*4+ks] — L1/L2-hot 8 KB by now
#pragma unroll
  for (int i = 0; i < 8; ++i)
    A2[i] = *(const bf16x8*)(w2p + ((size_t)i * 64 + lane) * 8);

  const f32x4 b2v = *(const f32x4*)(b2 + g * 4);
#pragma unroll
  for (int ni = 0; ni < 2; ++ni) {
    const int pxb = (wv * 2 + ni) * 16 + ln;
    const int sw = (pxb & 7) << 4;
    const int hbase = pxb * 256;
    f32x4 a = (f32x4){0.f, 0.f, 0.f, 0.f};
#pragma unroll
    for (int ks = 0; ks < 4; ++ks) {
      const bf16x8 Bf =
          *(const bf16x8*)((unsigned char*)Hs + ((hbase + ks * 64 + g * 16) ^ sw));
      a = __builtin_amdgcn_mfma_f32_16x16x32_bf16(A2[ks], Bf, a, 0, 0, 0);
      a = __builtin_amdgcn_mfma_f32_16x16x32_bf16(A2[4 + ks], Bf, a, 0, 0, 0);
    }
    const int wg = wt * 128 + pxb;
    const size_t pix = ((size_t)b * HH + h) * WW + wg;
    const float f = (float)fire[pix];
#pragma unroll
    for (int r = 0; r < 4; ++r) {
      const int c = g * 4 + r;
      const size_t xi = ((size_t)(b * CCH + c) * HH + h) * WW + wg;
      const float v = x[xi] + (a[r] + b2v[r]) * f;
      out[xi] = v;
      if (c == 3) alpha_ws[pix] = v;
    }
  }
}

// ---------------------------------------------------------------- life
__global__ __launch_bounds__(256) void life_mask_kernel(
    const float* __restrict__ alpha_ws, const unsigned char* __restrict__ pre_ws,
    float* __restrict__ out) {
  const int bh = blockIdx.x;
  const int b = bh >> 8;
  const int h = bh & 255;
  const int w = threadIdx.x;
  const int hm = (h + 255) & 255;
  const int hp = (h + 1) & 255;
  const int wm = (w + 255) & 255;
  const int wp = (w + 1) & 255;

  const float* ab = alpha_ws + (size_t)b * HH * WW;
  float m = ab[(size_t)hm * WW + wm];
  m = fmaxf(m, ab[(size_t)hm * WW + w]);
  m = fmaxf(m, ab[(size_t)hm * WW + wp]);
  m = fmaxf(m, ab[(size_t)h * WW + wm]);
  m = fmaxf(m, ab[(size_t)h * WW + w]);
  m = fmaxf(m, ab[(size_t)h * WW + wp]);
  m = fmaxf(m, ab[(size_t)hp * WW + wm]);
  m = fmaxf(m, ab[(size_t)hp * WW + w]);
  m = fmaxf(m, ab[(size_t)hp * WW + wp]);

  const size_t pix = ((size_t)b * HH + h) * WW + w;
  const bool post = m > 0.1f;
  const bool pre = pre_ws[pix] != 0;
  if (!(pre && post)) {
#pragma unroll
    for (int c = 0; c < CCH; ++c)
      out[((size_t)(b * CCH + c) * HH + h) * WW + w] = 0.0f;
  }
}

// ---------------------------------------------------------------- launch
extern "C" void kernel_launch(void* const* d_in, const int* in_sizes, int n_in,
                              void* d_out, int out_size, void* d_ws,
                              size_t ws_size, hipStream_t stream) {
  const float* x = (const float*)d_in[0];
  const float* w1 = (const float*)d_in[1];
  const float* b1 = (const float*)d_in[2];
  const float* w2 = (const float*)d_in[3];
  const float* b2 = (const float*)d_in[4];
  const int* fire = (const int*)d_in[5];
  float* out = (float*)d_out;

  const size_t npix = (size_t)BB * HH * WW;
  unsigned short* w1p = (unsigned short*)d_ws;
  unsigned short* w2p = (unsigned short*)((char*)d_ws + 32768);
  float* alpha_ws = (float*)((char*)d_ws + 40960);
  unsigned char* pre_ws = (unsigned char*)d_ws + 40960 + npix * sizeof(float);

  pack_w1_kernel<<<8, 256, 0, stream>>>(w1, w1p);
  pack_w2_kernel<<<2, 256, 0, stream>>>(w2, w2p);
  nca_mfma_kernel<<<BB * HH * 2, 256, 0, stream>>>(x, b1, b2, w1p, w2p, fire,
                                                   out, alpha_ws, pre_ws);
  life_mask_kernel<<<BB * HH, 256, 0, stream>>>(alpha_ws, pre_ws, out);
}